// Round 5
// baseline (1438.355 us; speedup 1.0000x reference)
//
#include <hip/hip_runtime.h>

#define HW 65536
#define IMG 256
// Blocked intermediate layout: [tile t = y/2][channel][512 px] — 2 KB per (t,c) granule.

__device__ __forceinline__ float hsum4(float4 v) { return v.x + v.y + v.z + v.w; }
__device__ __forceinline__ float lrelu(float v) { return v >= 0.f ? v : 0.2f * v; }

// ---------------- 1x1 conv (v8): burst-register staging ----------------
// Block = one image row r (256 px = 64 quads) x all CO. Thread = (lane=quad, wave=16 co).
// Per 16-ci chunk: 16 independent global_load_dwordx4 issued back-to-back (16 KB/wave in
// flight, no FMA interleaved in the issue train), then 256 FMA4s consume arrivals under
// the compiler's staggered vmcnt waits. Outer chunk loop rolled (I$); xbuf static-indexed.
// INB: input blocked [t][cs][512]; else NCHW. OUTB: output blocked; else NCHW.
// DUAL (requires INB): ci 0..63 from in, 64..127 from in2 (both blocked).
// stats: gsel==-1 -> group = co0>=32 ; gsel==-2 -> group = co0>=64 ; else group 0.
// GNIN: per-input-channel GN affine + leaky-relu applied to loaded values.
template<int CIT, int CO, bool GNIN, bool DUAL, bool INB, bool OUTB>
__global__ __launch_bounds__(CO*4)
void conv1x1_v8(const float* __restrict__ in, int in_cs, int in_coff,
                const float* __restrict__ in2, int in2_cs,
                const float* __restrict__ w, int w_bstride,
                const float* __restrict__ bias,
                float* __restrict__ out, int out_cs, int out_coff,
                float* __restrict__ stats, int gsel,
                const float* __restrict__ gstats,
                const float* __restrict__ g_gamma, const float* __restrict__ g_beta,
                int g_coff, float g_Nf)
{
    constexpr int NCH = CIT / 16;
    const int b    = blockIdx.y;
    const int r    = blockIdx.x;                   // image row 0..255
    const int lane = threadIdx.x & 63;             // quad within row
    const int wv   = __builtin_amdgcn_readfirstlane((int)(threadIdx.x >> 6));
    const int co0  = wv * 16;
    const float* wb = w + (size_t)b * w_bstride;

    float gmean = 0.f, grstd = 0.f;
    if (GNIN) {
        gmean = gstats[b*4] / g_Nf;
        float var = gstats[b*4 + 1] / g_Nf - gmean * gmean;
        grstd = rsqrtf(var + 1e-5f);
    }

    float4 acc[16];
    #pragma unroll
    for (int k = 0; k < 16; ++k) {
        float bv = bias ? bias[co0 + k] : 0.f;
        acc[k] = make_float4(bv, bv, bv, bv);
    }

    // per-tensor base addresses (float4 units)
    const float4* pA;
    size_t strA;
    if (INB) {
        pA = (const float4*)in + (size_t)b * in_cs * (HW/4)
           + ((size_t)(r >> 1) * in_cs + in_coff) * 128 + (size_t)(r & 1) * 64 + lane;
        strA = 128;
    } else {
        pA = (const float4*)in + ((size_t)b * in_cs + in_coff) * (HW/4)
           + (size_t)r * 64 + lane;
        strA = HW/4;
    }
    const float4* pB = nullptr;
    if (DUAL) {
        pB = (const float4*)in2 + (size_t)b * in2_cs * (HW/4)
           + (size_t)(r >> 1) * in2_cs * 128 + (size_t)(r & 1) * 64 + lane;
    }

    #pragma unroll 1
    for (int chk = 0; chk < NCH; ++chk) {
        const float4* base;
        size_t str;
        int lci0;
        if (DUAL && chk >= NCH/2) { base = pB; str = 128;  lci0 = (chk - NCH/2) * 16; }
        else                      { base = pA; str = strA; lci0 = chk * 16; }

        // ---- load train: 16 independent loads, no compute interleaved ----
        float4 xb[16];
        #pragma unroll
        for (int u = 0; u < 16; ++u)
            xb[u] = base[(size_t)(lci0 + u) * str];

        // ---- consume ----
        #pragma unroll
        for (int u = 0; u < 16; ++u) {
            const int gci = chk * 16 + u;          // global input-channel (weight row)
            float4 x = xb[u];
            if (GNIN) {
                float A = g_gamma[g_coff + gci] * grstd;
                float B = g_beta[g_coff + gci] - gmean * A;
                x.x = lrelu(fmaf(x.x, A, B));
                x.y = lrelu(fmaf(x.y, A, B));
                x.z = lrelu(fmaf(x.z, A, B));
                x.w = lrelu(fmaf(x.w, A, B));
            }
            const float* wr = wb + gci;
            #pragma unroll
            for (int k = 0; k < 16; ++k) {
                float wk = wr[(size_t)(co0 + k) * CIT];
                acc[k].x = fmaf(wk, x.x, acc[k].x);
                acc[k].y = fmaf(wk, x.y, acc[k].y);
                acc[k].z = fmaf(wk, x.z, acc[k].z);
                acc[k].w = fmaf(wk, x.w, acc[k].w);
            }
        }
    }

    if (!GNIN && stats) {
        float s = 0.f, ss = 0.f;
        #pragma unroll
        for (int k = 0; k < 16; ++k) {
            s  += acc[k].x + acc[k].y + acc[k].z + acc[k].w;
            ss += acc[k].x*acc[k].x + acc[k].y*acc[k].y
                + acc[k].z*acc[k].z + acc[k].w*acc[k].w;
        }
        #pragma unroll
        for (int o = 32; o; o >>= 1) { s += __shfl_down(s, o, 64); ss += __shfl_down(ss, o, 64); }
        if (lane == 0) {
            int g = 0;
            if (gsel == -1) g = (co0 >= 32) ? 1 : 0;
            else if (gsel == -2) g = (co0 >= 64) ? 1 : 0;
            float* st = stats + (size_t)b*4 + g*2;
            atomicAdd(st,     s);
            atomicAdd(st + 1, ss);
        }
    }

    #pragma unroll
    for (int k = 0; k < 16; ++k) {
        if (OUTB)
            ((float4*)out)[(size_t)b * out_cs * (HW/4)
                + ((size_t)(r >> 1) * out_cs + out_coff + co0 + k) * 128
                + (size_t)(r & 1) * 64 + lane] = acc[k];
        else
            ((float4*)out)[((size_t)b * out_cs + out_coff + co0 + k) * (HW/4)
                + (size_t)r * 64 + lane] = acc[k];
    }
}

// ---------------- fused depthwise 5x5(pad2) -> 3x3(dil3,pad3), blocked layout ----------------
// grid: (4, 8, nb*64), block 256. 64 channels per dispatch via in_coff/w_coff.
__global__ __launch_bounds__(256)
void dwfused(const float* __restrict__ in, int in_cs, int in_coff,
             const float* __restrict__ w5, const float* __restrict__ b5, int w5_coff,
             const float* __restrict__ w3, const float* __restrict__ b3, int w3_coff,
             float* __restrict__ out, int out_cs, int out_coff)
{
    constexpr int TH = 32, TW = 64;
    constexpr int IN_H = TH + 10, IN_W = TW + 10;
    constexpr int MID_H = TH + 6, MID_W = TW + 6;
    constexpr int IN_RS = IN_W + 2;
    constexpr int MID_RS = MID_W + 2;
    __shared__ float Xs[IN_H * IN_RS];
    __shared__ float Ms[MID_H * MID_RS];
    const int z = blockIdx.z;
    const int c = z & 63, b = z >> 6;
    const int x0 = blockIdx.x * TW, y0 = blockIdx.y * TH;
    const float* ib = in + (size_t)b * in_cs * HW;

    float wk5[25];
    #pragma unroll
    for (int i = 0; i < 25; ++i) wk5[i] = w5[(size_t)(w5_coff + c)*25 + i];
    const float bv5 = b5[w5_coff + c];
    float wk3[9];
    #pragma unroll
    for (int i = 0; i < 9; ++i) wk3[i] = w3[(size_t)(w3_coff + c)*9 + i];
    const float bv3 = b3[w3_coff + c];

    for (int idx = threadIdx.x; idx < IN_H*IN_W; idx += 256) {
        int ly = idx / IN_W, lx = idx - ly*IN_W;
        int gy = y0 + ly - 5, gx = x0 + lx - 5;
        float v = 0.f;
        if (gy >= 0 && gy < IMG && gx >= 0 && gx < IMG)
            v = ib[((size_t)(gy >> 1) * in_cs + in_coff + c) * 512 + (gy & 1) * 256 + gx];
        Xs[ly*IN_RS + lx] = v;
    }
    __syncthreads();

    for (int idx = threadIdx.x; idx < MID_H*MID_W; idx += 256) {
        int my = idx / MID_W, mx = idx - my*MID_W;
        int gy = y0 + my - 3, gx = x0 + mx - 3;
        float v = 0.f;
        if (gy >= 0 && gy < IMG && gx >= 0 && gx < IMG) {
            v = bv5;
            #pragma unroll
            for (int ky = 0; ky < 5; ++ky) {
                const float* xr = &Xs[(my + ky)*IN_RS + mx];
                #pragma unroll
                for (int kx = 0; kx < 5; ++kx)
                    v = fmaf(wk5[ky*5 + kx], xr[kx], v);
            }
        }
        Ms[my*MID_RS + mx] = v;
    }
    __syncthreads();

    const int qx = (threadIdx.x & 15) * 4;
    const int ly0 = threadIdx.x >> 4;
    float* ob = out + (size_t)b * out_cs * HW;
    #pragma unroll
    for (int r = 0; r < 2; ++r) {
        const int oy = ly0 + r*16;
        float o0 = bv3, o1 = bv3, o2 = bv3, o3 = bv3;
        #pragma unroll
        for (int kt = 0; kt < 3; ++kt) {
            const float* mr = &Ms[(oy + 3*kt)*MID_RS + qx];
            #pragma unroll
            for (int kx = 0; kx < 3; ++kx) {
                float wv_ = wk3[kt*3 + kx];
                o0 = fmaf(wv_, mr[3*kx + 0], o0);
                o1 = fmaf(wv_, mr[3*kx + 1], o1);
                o2 = fmaf(wv_, mr[3*kx + 2], o2);
                o3 = fmaf(wv_, mr[3*kx + 3], o3);
            }
        }
        const int y = y0 + oy;
        *(float4*)(ob + ((size_t)(y >> 1) * out_cs + out_coff + c) * 512 + (y & 1) * 256 + x0 + qx) =
            make_float4(o0, o1, o2, o3);
    }
}

// ---------------- attention raw dots (blocked q/k), GN+leaky fused + post-act sumsq ----------------
__global__ __launch_bounds__(256)
void attn_dot_v5(const float* __restrict__ qt, int q_cs,
                 const float* __restrict__ kt, int k_cs,
                 const float* __restrict__ stQ, const float* __restrict__ stK,
                 const float* __restrict__ qg, const float* __restrict__ qb,
                 const float* __restrict__ kg, const float* __restrict__ kb,
                 float* __restrict__ attn_raw,
                 float* __restrict__ ssq, float* __restrict__ ssk)
{
    __shared__ float4 qs[2048], ks[2048];
    __shared__ float sred[512];
    const int h = blockIdx.y, b = blockIdx.z;
    const int T = blockIdx.x;
    const int cc = threadIdx.x & 15;
    const int ch = h*16 + cc;

    const int gq = (ch >= 32) ? 1 : 0;
    float mq = stQ[b*4 + gq*2] / (32.f * HW);
    float vq = stQ[b*4 + gq*2 + 1] / (32.f * HW) - mq*mq;
    const float Aq = qg[ch] * rsqrtf(vq + 1e-5f);
    const float Bq = qb[ch] - mq * Aq;
    float mk = stK[b*4] / (64.f * HW);
    float vk = stK[b*4 + 1] / (64.f * HW) - mk*mk;
    const float Ak = kg[ch] * rsqrtf(vk + 1e-5f);
    const float Bk = kb[ch] - mk * Ak;

    const float4* q4 = (const float4*)qt + (size_t)b*q_cs*(HW/4) + ((size_t)T*q_cs + ch)*128;
    const float4* k4 = (const float4*)kt + (size_t)b*k_cs*(HW/4) + ((size_t)T*k_cs + ch)*128;
    float sq_acc = 0.f, sk_acc = 0.f;
    #pragma unroll
    for (int s = 0; s < 8; ++s) {
        int t = (threadIdx.x >> 4) + s*16;
        float4 v = q4[t];
        v.x = lrelu(fmaf(v.x, Aq, Bq)); v.y = lrelu(fmaf(v.y, Aq, Bq));
        v.z = lrelu(fmaf(v.z, Aq, Bq)); v.w = lrelu(fmaf(v.w, Aq, Bq));
        sq_acc += v.x*v.x + v.y*v.y + v.z*v.z + v.w*v.w;
        qs[t*16 + cc] = v;
        float4 u = k4[t];
        u.x = lrelu(fmaf(u.x, Ak, Bk)); u.y = lrelu(fmaf(u.y, Ak, Bk));
        u.z = lrelu(fmaf(u.z, Ak, Bk)); u.w = lrelu(fmaf(u.w, Ak, Bk));
        sk_acc += u.x*u.x + u.y*u.y + u.z*u.z + u.w*u.w;
        ks[t*16 + cc] = u;
    }
    sred[threadIdx.x]       = sq_acc;
    sred[256 + threadIdx.x] = sk_acc;
    __syncthreads();

    const int p   = threadIdx.x & 63;
    const int sub = threadIdx.x >> 6;
    const int c0 = (p >> 3) << 1, d0 = (p & 7) << 1;
    float4 a00 = make_float4(0,0,0,0), a01 = a00, a10 = a00, a11 = a00;
    #pragma unroll
    for (int i = 0; i < 32; ++i) {
        int t = sub*32 + i;
        float4 qa = qs[t*16 + c0], qb_ = qs[t*16 + c0 + 1];
        float4 ka = ks[t*16 + d0], kb_ = ks[t*16 + d0 + 1];
        a00.x = fmaf(qa.x, ka.x, a00.x); a00.y = fmaf(qa.y, ka.y, a00.y);
        a00.z = fmaf(qa.z, ka.z, a00.z); a00.w = fmaf(qa.w, ka.w, a00.w);
        a01.x = fmaf(qa.x, kb_.x, a01.x); a01.y = fmaf(qa.y, kb_.y, a01.y);
        a01.z = fmaf(qa.z, kb_.z, a01.z); a01.w = fmaf(qa.w, kb_.w, a01.w);
        a10.x = fmaf(qb_.x, ka.x, a10.x); a10.y = fmaf(qb_.y, ka.y, a10.y);
        a10.z = fmaf(qb_.z, ka.z, a10.z); a10.w = fmaf(qb_.w, ka.w, a10.w);
        a11.x = fmaf(qb_.x, kb_.x, a11.x); a11.y = fmaf(qb_.y, kb_.y, a11.y);
        a11.z = fmaf(qb_.z, kb_.z, a11.z); a11.w = fmaf(qb_.w, kb_.w, a11.w);
    }
    float* ar = attn_raw + ((size_t)b*4 + h) * 256;
    atomicAdd(&ar[(c0  )*16 + d0  ], hsum4(a00));
    atomicAdd(&ar[(c0  )*16 + d0+1], hsum4(a01));
    atomicAdd(&ar[(c0+1)*16 + d0  ], hsum4(a10));
    atomicAdd(&ar[(c0+1)*16 + d0+1], hsum4(a11));

    if (threadIdx.x < 16) {
        float s = 0.f;
        #pragma unroll
        for (int jj = 0; jj < 16; ++jj) s += sred[threadIdx.x + 16*jj];
        atomicAdd(&ssq[b*64 + h*16 + threadIdx.x], s);
    } else if (threadIdx.x < 32) {
        const int c2 = threadIdx.x - 16;
        float s = 0.f;
        #pragma unroll
        for (int jj = 0; jj < 16; ++jj) s += sred[256 + c2 + 16*jj];
        atomicAdd(&ssk[b*64 + h*16 + c2], s);
    }
}

// ---------------- softmax with l2-norm scaling + temperature ----------------
__global__ __launch_bounds__(256)
void attn_softmax_v2(const float* __restrict__ attn_raw,
                     const float* __restrict__ ssq, const float* __restrict__ ssk,
                     const float* __restrict__ temp, float* __restrict__ attn)
{
    const int h = blockIdx.x, b = blockIdx.y;
    const int c = threadIdx.x >> 4, d = threadIdx.x & 15;
    const float nq = fmaxf(sqrtf(ssq[b*64 + h*16 + c]), 1e-12f);
    const float nk = fmaxf(sqrtf(ssk[b*64 + h*16 + d]), 1e-12f);
    float logit = attn_raw[((size_t)b*4 + h)*256 + c*16 + d] / (nq * nk) * temp[h];
    float m = logit;
    #pragma unroll
    for (int o = 8; o; o >>= 1) m = fmaxf(m, __shfl_xor(m, o, 16));
    float e = expf(logit - m);
    float s = e;
    #pragma unroll
    for (int o = 8; o; o >>= 1) s += __shfl_xor(s, o, 16);
    attn[((size_t)b*4 + h)*256 + c*16 + d] = e / s;
}

// ---------------- M[b] = proj . blockdiag(attn[b]) ----------------
__global__ __launch_bounds__(256)
void build_m_v2(const float* __restrict__ attn, const float* __restrict__ proj_w,
                float* __restrict__ M)
{
    const int b = blockIdx.x;
    for (int i = threadIdx.x; i < 4096; i += 256) {
        int co = i >> 6, ci = i & 63;
        int h = ci >> 4, d = ci & 15;
        float s = 0.f;
        #pragma unroll
        for (int cc = 0; cc < 16; ++cc)
            s += proj_w[co*64 + h*16 + cc] * attn[((size_t)b*4 + h)*256 + cc*16 + d];
        M[(size_t)b*4096 + i] = s;
    }
}

extern "C" void kernel_launch(void* const* d_in, const int* in_sizes, int n_in,
                              void* d_out, int out_size, void* d_ws, size_t ws_size,
                              hipStream_t stream)
{
    const float* x       = (const float*)d_in[0];
    const float* y       = (const float*)d_in[1];
    const float* kv_w    = (const float*)d_in[2];
    const float* q_w     = (const float*)d_in[3];
    const float* proj_w  = (const float*)d_in[4];
    const float* kv_c0_w = (const float*)d_in[5];
    const float* kv_c0_b = (const float*)d_in[6];
    const float* kv_cs_w = (const float*)d_in[7];
    const float* kv_cs_b = (const float*)d_in[8];
    const float* kv_c1_w = (const float*)d_in[9];
    const float* kv_c1_b = (const float*)d_in[10];
    const float* kv_gn_g = (const float*)d_in[11];
    const float* kv_gn_b = (const float*)d_in[12];
    const float* q_c0_w  = (const float*)d_in[13];
    const float* q_c0_b  = (const float*)d_in[14];
    const float* q_cs_w  = (const float*)d_in[15];
    const float* q_cs_b  = (const float*)d_in[16];
    const float* q_c1_w  = (const float*)d_in[17];
    const float* q_c1_b  = (const float*)d_in[18];
    const float* q_gn_g  = (const float*)d_in[19];
    const float* q_gn_b  = (const float*)d_in[20];
    const float* temp    = (const float*)d_in[21];

    float* ws       = (float*)d_ws;
    float* statsKV  = ws;            // 4/batch  -> 16
    float* statsQ   = ws + 16;
    float* sumsq_k  = ws + 32;       // 64/batch -> 256
    float* sumsq_q  = ws + 288;
    float* attn_raw = ws + 544;      // 1024/batch -> 4096
    float* attn     = ws + 4640;
    float* Mw       = ws + 8736;     // 4096/batch -> 16384 (end 25120)
    float* big      = (float*)((char*)d_ws + 131072);

    const size_t perb_bytes = (size_t)192 * HW * 4;
    int nb = 1;
    if      (ws_size >= 131072 + 4*perb_bytes) nb = 4;
    else if (ws_size >= 131072 + 2*perb_bytes) nb = 2;

    hipMemsetAsync(d_ws, 0, 102400, stream);
    dim3 blk(256);

    for (int b0 = 0; b0 < 4; b0 += nb) {
        const float* xb = x + (size_t)b0*64*HW;
        const float* yb = y + (size_t)b0*64*HW;
        float* H1 = big;                          // nb*128*HW : kvpre out (blocked), later k|v_raw
        float* H2 = big + (size_t)nb*128*HW;      // nb*64*HW  : dw-out k-half, later q mid (blocked)
        float* O  = (float*)d_out + (size_t)b0*64*HW;   // nb*64*HW scratch: dw-out v-half, later q
        float* stK = statsKV + b0*4;
        float* stQ = statsQ  + b0*4;
        float* ssk = sumsq_k + b0*64;
        float* ssq = sumsq_q + b0*64;
        float* arw = attn_raw + b0*1024;
        float* atn = attn     + b0*1024;
        float* Mb  = Mw       + b0*4096;

        dim3 gdwf(4, 8, nb*64);
        dim3 gcv(256, nb);

        // ---- kv chain ----
        // y (NCHW) -> H1 blocked 128ch
        conv1x1_v8<64,128,false,false,false,true><<<gcv, dim3(512), 0, stream>>>(
            yb, 64, 0, nullptr, 0, kv_w, 0, nullptr, H1, 128, 0,
            nullptr, 0, nullptr, nullptr, nullptr, 0, 0.f);
        // fused dw5x5+dw3x3d3 (blocked in/out)
        dwfused<<<gdwf, blk, 0, stream>>>(H1, 128, 0,  kv_c0_w, kv_c0_b, 0,  kv_cs_w, kv_cs_b, 0,  H2, 64, 0);
        dwfused<<<gdwf, blk, 0, stream>>>(H1, 128, 64, kv_c0_w, kv_c0_b, 64, kv_cs_w, kv_cs_b, 64, O,  64, 0);
        // merged 128->128 1x1 (dual blocked input) -> H1 blocked: k(0:64) | v_raw(64:128), + GN stats
        conv1x1_v8<128,128,false,true,true,true><<<gcv, dim3(512), 0, stream>>>(
            H2, 64, 0, O, 64, kv_c1_w, 0, kv_c1_b, H1, 128, 0,
            stK, -2, nullptr, nullptr, nullptr, 0, 0.f);

        // ---- q chain ----
        conv1x1_v8<64,64,false,false,false,true><<<gcv, blk, 0, stream>>>(
            xb, 64, 0, nullptr, 0, q_w, 0, nullptr, O, 64, 0,
            nullptr, 0, nullptr, nullptr, nullptr, 0, 0.f);
        dwfused<<<gdwf, blk, 0, stream>>>(O, 64, 0, q_c0_w, q_c0_b, 0, q_cs_w, q_cs_b, 0, H2, 64, 0);
        conv1x1_v8<64,64,false,false,true,true><<<gcv, blk, 0, stream>>>(
            H2, 64, 0, nullptr, 0, q_c1_w, 0, q_c1_b, O, 64, 0,
            stQ, -1, nullptr, nullptr, nullptr, 0, 0.f);

        // ---- attention (blocked q=O cs64, k=H1 cs128) ----
        attn_dot_v5<<<dim3(128,4,nb), blk, 0, stream>>>(O, 64, H1, 128, stQ, stK,
                                                        q_gn_g, q_gn_b, kv_gn_g, kv_gn_b,
                                                        arw, ssq, ssk);
        attn_softmax_v2<<<dim3(4,nb), blk, 0, stream>>>(arw, ssq, ssk, temp, atn);
        build_m_v2<<<dim3(nb), blk, 0, stream>>>(atn, proj_w, Mb);

        // ---- out = M[b] @ leaky(GN(v_raw)); v_raw = H1 blocked coff 64; out NCHW d_out ----
        conv1x1_v8<64,64,true,false,true,false><<<gcv, blk, 0, stream>>>(
            H1, 128, 64, nullptr, 0, Mw + b0*4096, 4096, nullptr,
            (float*)d_out + (size_t)b0*64*HW, 64, 0,
            nullptr, 0, stK+2, kv_gn_g, kv_gn_b, 64, 64.f*HW);
    }
}

// Round 6
// 1164.434 us; speedup vs baseline: 1.2352x; 1.2352x over previous
//
#include <hip/hip_runtime.h>

#define HW 65536
#define IMG 256
// Blocked intermediate layout: [tile t = y/2][channel][512 px] — 2 KB per (t,c) granule.

__device__ __forceinline__ float hsum4(float4 v) { return v.x + v.y + v.z + v.w; }
__device__ __forceinline__ float lrelu(float v) { return v >= 0.f ? v : 0.2f * v; }

typedef const __attribute__((address_space(1))) unsigned int guint;
typedef __attribute__((address_space(3))) unsigned int luint;
__device__ __forceinline__ void gload_lds16(const float4* g, float4* l) {
    // direct global->LDS: per-lane global src, wave-uniform LDS base + lane*16
    __builtin_amdgcn_global_load_lds((guint*)(const void*)g, (luint*)(void*)l, 16, 0, 0);
}

// ---------------- 1x1 conv (v9): LDS-staged like the fast kernels ----------------
// Block = one 2-row tile T (512 px = 128 quads) x all CO. Threads = CO*8.
// Thread = (q = tid&127, coh = tid>>7); 16 co per thread. Input staged in big chunks
// (32 or 64 KB) into LDS via global_load_lds: dense load train, no dependent-FMA
// consumers in the issue stream -> 32-64 KB/CU outstanding while FMA phase runs.
// 4 chunks total, 4 barriers; stage(ch+1) issued right after barrier, compute(ch)
// (~4096 cy) covers its latency so the next barrier's vmcnt drain is ~free.
// INB: input blocked; else NCHW (1-KB row granules). OUTB likewise for output.
// DUAL (INB only): ci 0..63 from in, 64..127 from in2. CI_CHUNK=32 keeps chunks
// single-tensor. stats: gsel==-1 -> group = co0>=32 ; gsel==-2 -> co0>=64.
// GNIN: per-input-channel GN affine + leaky-relu applied after the LDS read.
template<int CIT, int CO, bool GNIN, bool DUAL, bool INB, bool OUTB>
__global__ __launch_bounds__(CO*8)
void conv1x1_v9(const float* __restrict__ in, int in_cs, int in_coff,
                const float* __restrict__ in2, int in2_cs,
                const float* __restrict__ w, int w_bstride,
                const float* __restrict__ bias,
                float* __restrict__ out, int out_cs, int out_coff,
                float* __restrict__ stats, int gsel,
                const float* __restrict__ gstats,
                const float* __restrict__ g_gamma, const float* __restrict__ g_beta,
                int g_coff, float g_Nf)
{
    constexpr int CI_CHUNK = (CIT == 128) ? 32 : 16;   // NCHUNK == 4 always
    constexpr int NCHUNK   = CIT / CI_CHUNK;
    constexpr int NW       = CO / 8;                   // waves per block
    constexpr int PPW      = CI_CHUNK * 2 / NW;        // 1-KB pieces per wave per chunk
    __shared__ float4 Xs[2][CI_CHUNK * 128];           // 2 x (32 or 64) KiB

    const int b    = blockIdx.y;
    const int T    = blockIdx.x;                       // 2-row tile
    const int q    = threadIdx.x & 127;                // quad within tile
    const int lane = threadIdx.x & 63;
    const int wv   = __builtin_amdgcn_readfirstlane((int)(threadIdx.x >> 6));
    const int coh  = __builtin_amdgcn_readfirstlane((int)(threadIdx.x >> 7));
    const int co0  = coh * 16;
    const float* wb = w + (size_t)b * w_bstride;

    float gmean = 0.f, grstd = 0.f;
    if (GNIN) {
        gmean = gstats[b*4] / g_Nf;
        float var = gstats[b*4 + 1] / g_Nf - gmean * gmean;
        grstd = rsqrtf(var + 1e-5f);
    }

    float4 acc[16];
    #pragma unroll
    for (int k = 0; k < 16; ++k) {
        float bv = bias ? bias[co0 + k] : 0.f;
        acc[k] = make_float4(bv, bv, bv, bv);
    }

    const float4* inA = (const float4*)in + (size_t)b * in_cs * (HW/4);
    const float4* inB = DUAL ? ((const float4*)in2 + (size_t)b * in2_cs * (HW/4)) : nullptr;

    // stage chunk ch into buffer bs: dense train of PPW global_load_lds per wave
    auto stage = [&](int ch, int bs) {
        #pragma unroll
        for (int u = 0; u < PPW; ++u) {
            const int piece = wv * PPW + u;            // 0 .. CI_CHUNK*2-1
            const int lci   = piece >> 1;
            const int half  = piece & 1;
            const int gci   = ch * CI_CHUNK + lci;
            const float4* src;
            if (INB) {
                if (DUAL && gci >= 64)
                    src = inB + ((size_t)T * in2_cs + (gci - 64)) * 128 + half * 64 + lane;
                else
                    src = inA + ((size_t)T * in_cs + in_coff + gci) * 128 + half * 64 + lane;
            } else {
                src = inA + (size_t)(in_coff + gci) * (HW/4) + (size_t)(T*2 + half) * 64 + lane;
            }
            gload_lds16(src, &Xs[bs][lci * 128 + half * 64]);
        }
    };

    auto compute = [&](int ch, int bs) {
        #pragma unroll 8
        for (int lci = 0; lci < CI_CHUNK; ++lci) {
            const int gci = ch * CI_CHUNK + lci;
            float4 x = Xs[bs][lci * 128 + q];
            if (GNIN) {
                float A = g_gamma[g_coff + gci] * grstd;
                float B = g_beta[g_coff + gci] - gmean * A;
                x.x = lrelu(fmaf(x.x, A, B));
                x.y = lrelu(fmaf(x.y, A, B));
                x.z = lrelu(fmaf(x.z, A, B));
                x.w = lrelu(fmaf(x.w, A, B));
            }
            const float* wr = wb + gci;
            #pragma unroll
            for (int k = 0; k < 16; ++k) {
                float wk = wr[(size_t)(co0 + k) * CIT];
                acc[k].x = fmaf(wk, x.x, acc[k].x);
                acc[k].y = fmaf(wk, x.y, acc[k].y);
                acc[k].z = fmaf(wk, x.z, acc[k].z);
                acc[k].w = fmaf(wk, x.w, acc[k].w);
            }
        }
    };

    stage(0, 0);
    #pragma unroll 1
    for (int ch = 0; ch < NCHUNK; ++ch) {
        __syncthreads();                       // chunk ch resident (drains its loads)
        if (ch + 1 < NCHUNK) stage(ch + 1, (ch + 1) & 1);
        compute(ch, ch & 1);
    }

    if (!GNIN && stats) {
        float s = 0.f, ss = 0.f;
        #pragma unroll
        for (int k = 0; k < 16; ++k) {
            s  += acc[k].x + acc[k].y + acc[k].z + acc[k].w;
            ss += acc[k].x*acc[k].x + acc[k].y*acc[k].y
                + acc[k].z*acc[k].z + acc[k].w*acc[k].w;
        }
        #pragma unroll
        for (int o = 32; o; o >>= 1) { s += __shfl_down(s, o, 64); ss += __shfl_down(ss, o, 64); }
        if (lane == 0) {
            int g = 0;
            if (gsel == -1) g = (co0 >= 32) ? 1 : 0;
            else if (gsel == -2) g = (co0 >= 64) ? 1 : 0;
            float* st = stats + (size_t)b*4 + g*2;
            atomicAdd(st,     s);
            atomicAdd(st + 1, ss);
        }
    }

    float4* ob = (float4*)out + (size_t)b * out_cs * (HW/4);
    #pragma unroll
    for (int k = 0; k < 16; ++k) {
        if (OUTB)
            ob[((size_t)T * out_cs + out_coff + co0 + k) * 128 + q] = acc[k];
        else
            ob[(size_t)(out_coff + co0 + k) * (HW/4) + (size_t)T * 128 + q] = acc[k];
    }
}

// ---------------- fused depthwise 5x5(pad2) -> 3x3(dil3,pad3), blocked layout ----------------
// grid: (4, 8, nb*64), block 256. 64 channels per dispatch via in_coff/w_coff.
__global__ __launch_bounds__(256)
void dwfused(const float* __restrict__ in, int in_cs, int in_coff,
             const float* __restrict__ w5, const float* __restrict__ b5, int w5_coff,
             const float* __restrict__ w3, const float* __restrict__ b3, int w3_coff,
             float* __restrict__ out, int out_cs, int out_coff)
{
    constexpr int TH = 32, TW = 64;
    constexpr int IN_H = TH + 10, IN_W = TW + 10;
    constexpr int MID_H = TH + 6, MID_W = TW + 6;
    constexpr int IN_RS = IN_W + 2;
    constexpr int MID_RS = MID_W + 2;
    __shared__ float Xs[IN_H * IN_RS];
    __shared__ float Ms[MID_H * MID_RS];
    const int z = blockIdx.z;
    const int c = z & 63, b = z >> 6;
    const int x0 = blockIdx.x * TW, y0 = blockIdx.y * TH;
    const float* ib = in + (size_t)b * in_cs * HW;

    float wk5[25];
    #pragma unroll
    for (int i = 0; i < 25; ++i) wk5[i] = w5[(size_t)(w5_coff + c)*25 + i];
    const float bv5 = b5[w5_coff + c];
    float wk3[9];
    #pragma unroll
    for (int i = 0; i < 9; ++i) wk3[i] = w3[(size_t)(w3_coff + c)*9 + i];
    const float bv3 = b3[w3_coff + c];

    for (int idx = threadIdx.x; idx < IN_H*IN_W; idx += 256) {
        int ly = idx / IN_W, lx = idx - ly*IN_W;
        int gy = y0 + ly - 5, gx = x0 + lx - 5;
        float v = 0.f;
        if (gy >= 0 && gy < IMG && gx >= 0 && gx < IMG)
            v = ib[((size_t)(gy >> 1) * in_cs + in_coff + c) * 512 + (gy & 1) * 256 + gx];
        Xs[ly*IN_RS + lx] = v;
    }
    __syncthreads();

    for (int idx = threadIdx.x; idx < MID_H*MID_W; idx += 256) {
        int my = idx / MID_W, mx = idx - my*MID_W;
        int gy = y0 + my - 3, gx = x0 + mx - 3;
        float v = 0.f;
        if (gy >= 0 && gy < IMG && gx >= 0 && gx < IMG) {
            v = bv5;
            #pragma unroll
            for (int ky = 0; ky < 5; ++ky) {
                const float* xr = &Xs[(my + ky)*IN_RS + mx];
                #pragma unroll
                for (int kx = 0; kx < 5; ++kx)
                    v = fmaf(wk5[ky*5 + kx], xr[kx], v);
            }
        }
        Ms[my*MID_RS + mx] = v;
    }
    __syncthreads();

    const int qx = (threadIdx.x & 15) * 4;
    const int ly0 = threadIdx.x >> 4;
    float* ob = out + (size_t)b * out_cs * HW;
    #pragma unroll
    for (int r = 0; r < 2; ++r) {
        const int oy = ly0 + r*16;
        float o0 = bv3, o1 = bv3, o2 = bv3, o3 = bv3;
        #pragma unroll
        for (int kt = 0; kt < 3; ++kt) {
            const float* mr = &Ms[(oy + 3*kt)*MID_RS + qx];
            #pragma unroll
            for (int kx = 0; kx < 3; ++kx) {
                float wv_ = wk3[kt*3 + kx];
                o0 = fmaf(wv_, mr[3*kx + 0], o0);
                o1 = fmaf(wv_, mr[3*kx + 1], o1);
                o2 = fmaf(wv_, mr[3*kx + 2], o2);
                o3 = fmaf(wv_, mr[3*kx + 3], o3);
            }
        }
        const int y = y0 + oy;
        *(float4*)(ob + ((size_t)(y >> 1) * out_cs + out_coff + c) * 512 + (y & 1) * 256 + x0 + qx) =
            make_float4(o0, o1, o2, o3);
    }
}

// ---------------- attention raw dots (blocked q/k), GN+leaky fused + post-act sumsq ----------------
__global__ __launch_bounds__(256)
void attn_dot_v5(const float* __restrict__ qt, int q_cs,
                 const float* __restrict__ kt, int k_cs,
                 const float* __restrict__ stQ, const float* __restrict__ stK,
                 const float* __restrict__ qg, const float* __restrict__ qb,
                 const float* __restrict__ kg, const float* __restrict__ kb,
                 float* __restrict__ attn_raw,
                 float* __restrict__ ssq, float* __restrict__ ssk)
{
    __shared__ float4 qs[2048], ks[2048];
    __shared__ float sred[512];
    const int h = blockIdx.y, b = blockIdx.z;
    const int T = blockIdx.x;
    const int cc = threadIdx.x & 15;
    const int ch = h*16 + cc;

    const int gq = (ch >= 32) ? 1 : 0;
    float mq = stQ[b*4 + gq*2] / (32.f * HW);
    float vq = stQ[b*4 + gq*2 + 1] / (32.f * HW) - mq*mq;
    const float Aq = qg[ch] * rsqrtf(vq + 1e-5f);
    const float Bq = qb[ch] - mq * Aq;
    float mk = stK[b*4] / (64.f * HW);
    float vk = stK[b*4 + 1] / (64.f * HW) - mk*mk;
    const float Ak = kg[ch] * rsqrtf(vk + 1e-5f);
    const float Bk = kb[ch] - mk * Ak;

    const float4* q4 = (const float4*)qt + (size_t)b*q_cs*(HW/4) + ((size_t)T*q_cs + ch)*128;
    const float4* k4 = (const float4*)kt + (size_t)b*k_cs*(HW/4) + ((size_t)T*k_cs + ch)*128;
    float sq_acc = 0.f, sk_acc = 0.f;
    #pragma unroll
    for (int s = 0; s < 8; ++s) {
        int t = (threadIdx.x >> 4) + s*16;
        float4 v = q4[t];
        v.x = lrelu(fmaf(v.x, Aq, Bq)); v.y = lrelu(fmaf(v.y, Aq, Bq));
        v.z = lrelu(fmaf(v.z, Aq, Bq)); v.w = lrelu(fmaf(v.w, Aq, Bq));
        sq_acc += v.x*v.x + v.y*v.y + v.z*v.z + v.w*v.w;
        qs[t*16 + cc] = v;
        float4 u = k4[t];
        u.x = lrelu(fmaf(u.x, Ak, Bk)); u.y = lrelu(fmaf(u.y, Ak, Bk));
        u.z = lrelu(fmaf(u.z, Ak, Bk)); u.w = lrelu(fmaf(u.w, Ak, Bk));
        sk_acc += u.x*u.x + u.y*u.y + u.z*u.z + u.w*u.w;
        ks[t*16 + cc] = u;
    }
    sred[threadIdx.x]       = sq_acc;
    sred[256 + threadIdx.x] = sk_acc;
    __syncthreads();

    const int p   = threadIdx.x & 63;
    const int sub = threadIdx.x >> 6;
    const int c0 = (p >> 3) << 1, d0 = (p & 7) << 1;
    float4 a00 = make_float4(0,0,0,0), a01 = a00, a10 = a00, a11 = a00;
    #pragma unroll
    for (int i = 0; i < 32; ++i) {
        int t = sub*32 + i;
        float4 qa = qs[t*16 + c0], qb_ = qs[t*16 + c0 + 1];
        float4 ka = ks[t*16 + d0], kb_ = ks[t*16 + d0 + 1];
        a00.x = fmaf(qa.x, ka.x, a00.x); a00.y = fmaf(qa.y, ka.y, a00.y);
        a00.z = fmaf(qa.z, ka.z, a00.z); a00.w = fmaf(qa.w, ka.w, a00.w);
        a01.x = fmaf(qa.x, kb_.x, a01.x); a01.y = fmaf(qa.y, kb_.y, a01.y);
        a01.z = fmaf(qa.z, kb_.z, a01.z); a01.w = fmaf(qa.w, kb_.w, a01.w);
        a10.x = fmaf(qb_.x, ka.x, a10.x); a10.y = fmaf(qb_.y, ka.y, a10.y);
        a10.z = fmaf(qb_.z, ka.z, a10.z); a10.w = fmaf(qb_.w, ka.w, a10.w);
        a11.x = fmaf(qb_.x, kb_.x, a11.x); a11.y = fmaf(qb_.y, kb_.y, a11.y);
        a11.z = fmaf(qb_.z, kb_.z, a11.z); a11.w = fmaf(qb_.w, kb_.w, a11.w);
    }
    float* ar = attn_raw + ((size_t)b*4 + h) * 256;
    atomicAdd(&ar[(c0  )*16 + d0  ], hsum4(a00));
    atomicAdd(&ar[(c0  )*16 + d0+1], hsum4(a01));
    atomicAdd(&ar[(c0+1)*16 + d0  ], hsum4(a10));
    atomicAdd(&ar[(c0+1)*16 + d0+1], hsum4(a11));

    if (threadIdx.x < 16) {
        float s = 0.f;
        #pragma unroll
        for (int jj = 0; jj < 16; ++jj) s += sred[threadIdx.x + 16*jj];
        atomicAdd(&ssq[b*64 + h*16 + threadIdx.x], s);
    } else if (threadIdx.x < 32) {
        const int c2 = threadIdx.x - 16;
        float s = 0.f;
        #pragma unroll
        for (int jj = 0; jj < 16; ++jj) s += sred[256 + c2 + 16*jj];
        atomicAdd(&ssk[b*64 + h*16 + c2], s);
    }
}

// ---------------- softmax with l2-norm scaling + temperature ----------------
__global__ __launch_bounds__(256)
void attn_softmax_v2(const float* __restrict__ attn_raw,
                     const float* __restrict__ ssq, const float* __restrict__ ssk,
                     const float* __restrict__ temp, float* __restrict__ attn)
{
    const int h = blockIdx.x, b = blockIdx.y;
    const int c = threadIdx.x >> 4, d = threadIdx.x & 15;
    const float nq = fmaxf(sqrtf(ssq[b*64 + h*16 + c]), 1e-12f);
    const float nk = fmaxf(sqrtf(ssk[b*64 + h*16 + d]), 1e-12f);
    float logit = attn_raw[((size_t)b*4 + h)*256 + c*16 + d] / (nq * nk) * temp[h];
    float m = logit;
    #pragma unroll
    for (int o = 8; o; o >>= 1) m = fmaxf(m, __shfl_xor(m, o, 16));
    float e = expf(logit - m);
    float s = e;
    #pragma unroll
    for (int o = 8; o; o >>= 1) s += __shfl_xor(s, o, 16);
    attn[((size_t)b*4 + h)*256 + c*16 + d] = e / s;
}

// ---------------- M[b] = proj . blockdiag(attn[b]) ----------------
__global__ __launch_bounds__(256)
void build_m_v2(const float* __restrict__ attn, const float* __restrict__ proj_w,
                float* __restrict__ M)
{
    const int b = blockIdx.x;
    for (int i = threadIdx.x; i < 4096; i += 256) {
        int co = i >> 6, ci = i & 63;
        int h = ci >> 4, d = ci & 15;
        float s = 0.f;
        #pragma unroll
        for (int cc = 0; cc < 16; ++cc)
            s += proj_w[co*64 + h*16 + cc] * attn[((size_t)b*4 + h)*256 + cc*16 + d];
        M[(size_t)b*4096 + i] = s;
    }
}

extern "C" void kernel_launch(void* const* d_in, const int* in_sizes, int n_in,
                              void* d_out, int out_size, void* d_ws, size_t ws_size,
                              hipStream_t stream)
{
    const float* x       = (const float*)d_in[0];
    const float* y       = (const float*)d_in[1];
    const float* kv_w    = (const float*)d_in[2];
    const float* q_w     = (const float*)d_in[3];
    const float* proj_w  = (const float*)d_in[4];
    const float* kv_c0_w = (const float*)d_in[5];
    const float* kv_c0_b = (const float*)d_in[6];
    const float* kv_cs_w = (const float*)d_in[7];
    const float* kv_cs_b = (const float*)d_in[8];
    const float* kv_c1_w = (const float*)d_in[9];
    const float* kv_c1_b = (const float*)d_in[10];
    const float* kv_gn_g = (const float*)d_in[11];
    const float* kv_gn_b = (const float*)d_in[12];
    const float* q_c0_w  = (const float*)d_in[13];
    const float* q_c0_b  = (const float*)d_in[14];
    const float* q_cs_w  = (const float*)d_in[15];
    const float* q_cs_b  = (const float*)d_in[16];
    const float* q_c1_w  = (const float*)d_in[17];
    const float* q_c1_b  = (const float*)d_in[18];
    const float* q_gn_g  = (const float*)d_in[19];
    const float* q_gn_b  = (const float*)d_in[20];
    const float* temp    = (const float*)d_in[21];

    float* ws       = (float*)d_ws;
    float* statsKV  = ws;            // 4/batch  -> 16
    float* statsQ   = ws + 16;
    float* sumsq_k  = ws + 32;       // 64/batch -> 256
    float* sumsq_q  = ws + 288;
    float* attn_raw = ws + 544;      // 1024/batch -> 4096
    float* attn     = ws + 4640;
    float* Mw       = ws + 8736;     // 4096/batch -> 16384 (end 25120)
    float* big      = (float*)((char*)d_ws + 131072);

    const size_t perb_bytes = (size_t)192 * HW * 4;
    int nb = 1;
    if      (ws_size >= 131072 + 4*perb_bytes) nb = 4;
    else if (ws_size >= 131072 + 2*perb_bytes) nb = 2;

    hipMemsetAsync(d_ws, 0, 102400, stream);
    dim3 blk(256);

    for (int b0 = 0; b0 < 4; b0 += nb) {
        const float* xb = x + (size_t)b0*64*HW;
        const float* yb = y + (size_t)b0*64*HW;
        float* H1 = big;                          // nb*128*HW : kvpre out (blocked), later k|v_raw
        float* H2 = big + (size_t)nb*128*HW;      // nb*64*HW  : dw-out k-half, later q mid (blocked)
        float* O  = (float*)d_out + (size_t)b0*64*HW;   // nb*64*HW scratch: dw-out v-half, later q
        float* stK = statsKV + b0*4;
        float* stQ = statsQ  + b0*4;
        float* ssk = sumsq_k + b0*64;
        float* ssq = sumsq_q + b0*64;
        float* arw = attn_raw + b0*1024;
        float* atn = attn     + b0*1024;
        float* Mb  = Mw       + b0*4096;

        dim3 gdwf(4, 8, nb*64);
        dim3 gcv(128, nb);

        // ---- kv chain ----
        // y (NCHW) -> H1 blocked 128ch
        conv1x1_v9<64,128,false,false,false,true><<<gcv, dim3(1024), 0, stream>>>(
            yb, 64, 0, nullptr, 0, kv_w, 0, nullptr, H1, 128, 0,
            nullptr, 0, nullptr, nullptr, nullptr, 0, 0.f);
        // fused dw5x5+dw3x3d3 (blocked in/out)
        dwfused<<<gdwf, blk, 0, stream>>>(H1, 128, 0,  kv_c0_w, kv_c0_b, 0,  kv_cs_w, kv_cs_b, 0,  H2, 64, 0);
        dwfused<<<gdwf, blk, 0, stream>>>(H1, 128, 64, kv_c0_w, kv_c0_b, 64, kv_cs_w, kv_cs_b, 64, O,  64, 0);
        // merged 128->128 1x1 (dual blocked input) -> H1 blocked: k(0:64) | v_raw(64:128), + GN stats
        conv1x1_v9<128,128,false,true,true,true><<<gcv, dim3(1024), 0, stream>>>(
            H2, 64, 0, O, 64, kv_c1_w, 0, kv_c1_b, H1, 128, 0,
            stK, -2, nullptr, nullptr, nullptr, 0, 0.f);

        // ---- q chain ----
        conv1x1_v9<64,64,false,false,false,true><<<gcv, dim3(512), 0, stream>>>(
            xb, 64, 0, nullptr, 0, q_w, 0, nullptr, O, 64, 0,
            nullptr, 0, nullptr, nullptr, nullptr, 0, 0.f);
        dwfused<<<gdwf, blk, 0, stream>>>(O, 64, 0, q_c0_w, q_c0_b, 0, q_cs_w, q_cs_b, 0, H2, 64, 0);
        conv1x1_v9<64,64,false,false,true,true><<<gcv, dim3(512), 0, stream>>>(
            H2, 64, 0, nullptr, 0, q_c1_w, 0, q_c1_b, O, 64, 0,
            stQ, -1, nullptr, nullptr, nullptr, 0, 0.f);

        // ---- attention (blocked q=O cs64, k=H1 cs128) ----
        attn_dot_v5<<<dim3(128,4,nb), blk, 0, stream>>>(O, 64, H1, 128, stQ, stK,
                                                        q_gn_g, q_gn_b, kv_gn_g, kv_gn_b,
                                                        arw, ssq, ssk);
        attn_softmax_v2<<<dim3(4,nb), blk, 0, stream>>>(arw, ssq, ssk, temp, atn);
        build_m_v2<<<dim3(nb), blk, 0, stream>>>(atn, proj_w, Mb);

        // ---- out = M[b] @ leaky(GN(v_raw)); v_raw = H1 blocked coff 64; out NCHW d_out ----
        conv1x1_v9<64,64,true,false,true,false><<<gcv, dim3(512), 0, stream>>>(
            H1, 128, 64, nullptr, 0, Mw + b0*4096, 4096, nullptr,
            (float*)d_out + (size_t)b0*64*HW, 64, 0,
            nullptr, 0, stK+2, kv_gn_g, kv_gn_b, 64, 64.f*HW);
    }
}

// Round 7
// 928.326 us; speedup vs baseline: 1.5494x; 1.2543x over previous
//
#include <hip/hip_runtime.h>

#define HW 65536
#define IMG 256
// Blocked intermediate layout: [tile t = y/2][channel][512 px].
// fp32 granule 2 KB, bf16 granule 1 KB per (t,c).

__device__ __forceinline__ float hsum4(float4 v) { return v.x + v.y + v.z + v.w; }
__device__ __forceinline__ float lrelu(float v) { return v >= 0.f ? v : 0.2f * v; }
__device__ __forceinline__ float bf2f(unsigned short u) {
    return __uint_as_float(((unsigned)u) << 16);
}
__device__ __forceinline__ unsigned short f2bf(float f) {   // round-to-nearest-even
    unsigned i = __float_as_uint(f);
    return (unsigned short)((i + 0x7FFFu + ((i >> 16) & 1u)) >> 16);
}
__device__ __forceinline__ float4 dq4(ushort4 u) {
    return make_float4(bf2f(u.x), bf2f(u.y), bf2f(u.z), bf2f(u.w));
}
__device__ __forceinline__ ushort4 qz4(float4 v) {
    ushort4 u; u.x = f2bf(v.x); u.y = f2bf(v.y); u.z = f2bf(v.z); u.w = f2bf(v.w);
    return u;
}

// ---------------- 1x1 conv (v10): v7 structure + bf16 I/O modes ----------------
// Block = one 2-row tile T (512 px = 128 quads) x all CO. Threads = CO*8.
// Thread = (q = tid&127, coh = tid>>7 wave-uniform); 16 co per thread.
// Inner loop = proven v3/v7 pattern (1 load + 16 FMA4 per ci, unroll 4).
// INM: 0 = NCHW fp32, 1 = blocked fp32, 2 = blocked bf16.
// OUTM: 0 = NCHW fp32, 2 = blocked bf16.
// stats (fp32, from fp32 accumulators BEFORE bf16 store):
//   gsel==-1 -> group = co0>=32 ; gsel==-2 -> group = co0>=64 ; else group 0.
// GNIN: per-input-channel GN affine + leaky-relu applied after dequant.
template<int CIT, int CO, int INM, int OUTM, bool GNIN>
__global__ __launch_bounds__(CO*8)
void conv1x1_v10(const void* __restrict__ in, int in_cs, int in_coff,
                 const float* __restrict__ w, int w_bstride,
                 const float* __restrict__ bias,
                 void* __restrict__ out, int out_cs, int out_coff,
                 float* __restrict__ stats, int gsel,
                 const float* __restrict__ gstats,
                 const float* __restrict__ g_gamma, const float* __restrict__ g_beta,
                 int g_coff, float g_Nf)
{
    const int b   = blockIdx.y;
    const int T   = blockIdx.x;                 // 2-row tile
    const int q   = threadIdx.x & 127;          // quad within tile
    const int lane = threadIdx.x & 63;
    const int coh = __builtin_amdgcn_readfirstlane((int)(threadIdx.x >> 7));
    const int co0 = coh * 16;
    const float* wb = w + (size_t)b * w_bstride;

    float gmean = 0.f, grstd = 0.f;
    if (GNIN) {
        gmean = gstats[b*4] / g_Nf;
        float var = gstats[b*4 + 1] / g_Nf - gmean * gmean;
        grstd = rsqrtf(var + 1e-5f);
    }

    float4 acc[16];
    #pragma unroll
    for (int k = 0; k < 16; ++k) {
        float bv = bias ? bias[co0 + k] : 0.f;
        acc[k] = make_float4(bv, bv, bv, bv);
    }

    const float4*  bf4 = nullptr;
    const ushort4* bu4 = nullptr;
    size_t cstr;
    if (INM == 0) {
        bf4 = (const float4*)in + ((size_t)b * in_cs + in_coff) * (HW/4)
            + (size_t)T * 128 + q;
        cstr = HW/4;
    } else if (INM == 1) {
        bf4 = (const float4*)in + (size_t)b * in_cs * (HW/4)
            + ((size_t)T * in_cs + in_coff) * 128 + q;
        cstr = 128;
    } else {
        bu4 = (const ushort4*)in + (size_t)b * in_cs * (HW/4)
            + ((size_t)T * in_cs + in_coff) * 128 + q;
        cstr = 128;
    }

    #pragma unroll 4
    for (int ci = 0; ci < CIT; ++ci) {
        float4 x = (INM == 2) ? dq4(bu4[(size_t)ci * cstr]) : bf4[(size_t)ci * cstr];
        if (GNIN) {
            float A = g_gamma[g_coff + ci] * grstd;
            float B = g_beta[g_coff + ci] - gmean * A;
            x.x = lrelu(fmaf(x.x, A, B));
            x.y = lrelu(fmaf(x.y, A, B));
            x.z = lrelu(fmaf(x.z, A, B));
            x.w = lrelu(fmaf(x.w, A, B));
        }
        const float* wr = wb + ci;
        #pragma unroll
        for (int k = 0; k < 16; ++k) {
            float wk = wr[(size_t)(co0 + k) * CIT];
            acc[k].x = fmaf(wk, x.x, acc[k].x);
            acc[k].y = fmaf(wk, x.y, acc[k].y);
            acc[k].z = fmaf(wk, x.z, acc[k].z);
            acc[k].w = fmaf(wk, x.w, acc[k].w);
        }
    }

    if (!GNIN && stats) {
        float s = 0.f, ss = 0.f;
        #pragma unroll
        for (int k = 0; k < 16; ++k) {
            s  += acc[k].x + acc[k].y + acc[k].z + acc[k].w;
            ss += acc[k].x*acc[k].x + acc[k].y*acc[k].y
                + acc[k].z*acc[k].z + acc[k].w*acc[k].w;
        }
        #pragma unroll
        for (int o = 32; o; o >>= 1) { s += __shfl_down(s, o, 64); ss += __shfl_down(ss, o, 64); }
        if (lane == 0) {
            int g = 0;
            if (gsel == -1) g = (co0 >= 32) ? 1 : 0;
            else if (gsel == -2) g = (co0 >= 64) ? 1 : 0;
            float* st = stats + (size_t)b*4 + g*2;
            atomicAdd(st,     s);
            atomicAdd(st + 1, ss);
        }
    }

    if (OUTM == 0) {
        float4* ob = (float4*)out + (size_t)b * out_cs * (HW/4);
        #pragma unroll
        for (int k = 0; k < 16; ++k)
            ob[(size_t)(out_coff + co0 + k) * (HW/4) + (size_t)T * 128 + q] = acc[k];
    } else {
        ushort4* ob = (ushort4*)out + (size_t)b * out_cs * (HW/4);
        #pragma unroll
        for (int k = 0; k < 16; ++k)
            ob[((size_t)T * out_cs + out_coff + co0 + k) * 128 + q] = qz4(acc[k]);
    }
}

// ---------------- fused depthwise 5x5(pad2) -> 3x3(dil3,pad3), blocked bf16 ----------------
// grid: (4, 8, nb*64), block 256. 64 channels per dispatch via in_coff/w_coff.
// Compute in fp32 (LDS fp32); I/O bf16 blocked [t][cs][512].
__global__ __launch_bounds__(256)
void dwfused16(const unsigned short* __restrict__ in, int in_cs, int in_coff,
               const float* __restrict__ w5, const float* __restrict__ b5, int w5_coff,
               const float* __restrict__ w3, const float* __restrict__ b3, int w3_coff,
               unsigned short* __restrict__ out, int out_cs, int out_coff)
{
    constexpr int TH = 32, TW = 64;
    constexpr int IN_H = TH + 10, IN_W = TW + 10;
    constexpr int MID_H = TH + 6, MID_W = TW + 6;
    constexpr int IN_RS = IN_W + 2;
    constexpr int MID_RS = MID_W + 2;
    __shared__ float Xs[IN_H * IN_RS];
    __shared__ float Ms[MID_H * MID_RS];
    const int z = blockIdx.z;
    const int c = z & 63, b = z >> 6;
    const int x0 = blockIdx.x * TW, y0 = blockIdx.y * TH;
    const unsigned short* ib = in + (size_t)b * in_cs * HW;

    float wk5[25];
    #pragma unroll
    for (int i = 0; i < 25; ++i) wk5[i] = w5[(size_t)(w5_coff + c)*25 + i];
    const float bv5 = b5[w5_coff + c];
    float wk3[9];
    #pragma unroll
    for (int i = 0; i < 9; ++i) wk3[i] = w3[(size_t)(w3_coff + c)*9 + i];
    const float bv3 = b3[w3_coff + c];

    for (int idx = threadIdx.x; idx < IN_H*IN_W; idx += 256) {
        int ly = idx / IN_W, lx = idx - ly*IN_W;
        int gy = y0 + ly - 5, gx = x0 + lx - 5;
        float v = 0.f;
        if (gy >= 0 && gy < IMG && gx >= 0 && gx < IMG)
            v = bf2f(ib[((size_t)(gy >> 1) * in_cs + in_coff + c) * 512 + (gy & 1) * 256 + gx]);
        Xs[ly*IN_RS + lx] = v;
    }
    __syncthreads();

    for (int idx = threadIdx.x; idx < MID_H*MID_W; idx += 256) {
        int my = idx / MID_W, mx = idx - my*MID_W;
        int gy = y0 + my - 3, gx = x0 + mx - 3;
        float v = 0.f;
        if (gy >= 0 && gy < IMG && gx >= 0 && gx < IMG) {
            v = bv5;
            #pragma unroll
            for (int ky = 0; ky < 5; ++ky) {
                const float* xr = &Xs[(my + ky)*IN_RS + mx];
                #pragma unroll
                for (int kx = 0; kx < 5; ++kx)
                    v = fmaf(wk5[ky*5 + kx], xr[kx], v);
            }
        }
        Ms[my*MID_RS + mx] = v;
    }
    __syncthreads();

    const int qx = (threadIdx.x & 15) * 4;
    const int ly0 = threadIdx.x >> 4;
    unsigned short* ob = out + (size_t)b * out_cs * HW;
    #pragma unroll
    for (int r = 0; r < 2; ++r) {
        const int oy = ly0 + r*16;
        float o0 = bv3, o1 = bv3, o2 = bv3, o3 = bv3;
        #pragma unroll
        for (int kt = 0; kt < 3; ++kt) {
            const float* mr = &Ms[(oy + 3*kt)*MID_RS + qx];
            #pragma unroll
            for (int kx = 0; kx < 3; ++kx) {
                float wv_ = wk3[kt*3 + kx];
                o0 = fmaf(wv_, mr[3*kx + 0], o0);
                o1 = fmaf(wv_, mr[3*kx + 1], o1);
                o2 = fmaf(wv_, mr[3*kx + 2], o2);
                o3 = fmaf(wv_, mr[3*kx + 3], o3);
            }
        }
        const int y = y0 + oy;
        *(ushort4*)(ob + ((size_t)(y >> 1) * out_cs + out_coff + c) * 512 + (y & 1) * 256 + x0 + qx) =
            qz4(make_float4(o0, o1, o2, o3));
    }
}

// ---------------- attention raw dots (blocked bf16 q/k), GN+leaky fused + sumsq ----------------
// grid: (128, 4, nb), block 256. Block = one 2-row tile T.
__global__ __launch_bounds__(256)
void attn_dot_v6(const unsigned short* __restrict__ qt, int q_cs,
                 const unsigned short* __restrict__ kt, int k_cs,
                 const float* __restrict__ stQ, const float* __restrict__ stK,
                 const float* __restrict__ qg, const float* __restrict__ qb,
                 const float* __restrict__ kg, const float* __restrict__ kb,
                 float* __restrict__ attn_raw,
                 float* __restrict__ ssq, float* __restrict__ ssk)
{
    __shared__ float4 qs[2048], ks[2048];
    __shared__ float sred[512];
    const int h = blockIdx.y, b = blockIdx.z;
    const int T = blockIdx.x;
    const int cc = threadIdx.x & 15;
    const int ch = h*16 + cc;

    const int gq = (ch >= 32) ? 1 : 0;
    float mq = stQ[b*4 + gq*2] / (32.f * HW);
    float vq = stQ[b*4 + gq*2 + 1] / (32.f * HW) - mq*mq;
    const float Aq = qg[ch] * rsqrtf(vq + 1e-5f);
    const float Bq = qb[ch] - mq * Aq;
    float mk = stK[b*4] / (64.f * HW);
    float vk = stK[b*4 + 1] / (64.f * HW) - mk*mk;
    const float Ak = kg[ch] * rsqrtf(vk + 1e-5f);
    const float Bk = kb[ch] - mk * Ak;

    const ushort4* q4 = (const ushort4*)qt + (size_t)b*q_cs*(HW/4) + ((size_t)T*q_cs + ch)*128;
    const ushort4* k4 = (const ushort4*)kt + (size_t)b*k_cs*(HW/4) + ((size_t)T*k_cs + ch)*128;
    float sq_acc = 0.f, sk_acc = 0.f;
    #pragma unroll
    for (int s = 0; s < 8; ++s) {
        int t = (threadIdx.x >> 4) + s*16;
        float4 v = dq4(q4[t]);
        v.x = lrelu(fmaf(v.x, Aq, Bq)); v.y = lrelu(fmaf(v.y, Aq, Bq));
        v.z = lrelu(fmaf(v.z, Aq, Bq)); v.w = lrelu(fmaf(v.w, Aq, Bq));
        sq_acc += v.x*v.x + v.y*v.y + v.z*v.z + v.w*v.w;
        qs[t*16 + cc] = v;
        float4 u = dq4(k4[t]);
        u.x = lrelu(fmaf(u.x, Ak, Bk)); u.y = lrelu(fmaf(u.y, Ak, Bk));
        u.z = lrelu(fmaf(u.z, Ak, Bk)); u.w = lrelu(fmaf(u.w, Ak, Bk));
        sk_acc += u.x*u.x + u.y*u.y + u.z*u.z + u.w*u.w;
        ks[t*16 + cc] = u;
    }
    sred[threadIdx.x]       = sq_acc;
    sred[256 + threadIdx.x] = sk_acc;
    __syncthreads();

    const int p   = threadIdx.x & 63;
    const int sub = threadIdx.x >> 6;
    const int c0 = (p >> 3) << 1, d0 = (p & 7) << 1;
    float4 a00 = make_float4(0,0,0,0), a01 = a00, a10 = a00, a11 = a00;
    #pragma unroll
    for (int i = 0; i < 32; ++i) {
        int t = sub*32 + i;
        float4 qa = qs[t*16 + c0], qb_ = qs[t*16 + c0 + 1];
        float4 ka = ks[t*16 + d0], kb_ = ks[t*16 + d0 + 1];
        a00.x = fmaf(qa.x, ka.x, a00.x); a00.y = fmaf(qa.y, ka.y, a00.y);
        a00.z = fmaf(qa.z, ka.z, a00.z); a00.w = fmaf(qa.w, ka.w, a00.w);
        a01.x = fmaf(qa.x, kb_.x, a01.x); a01.y = fmaf(qa.y, kb_.y, a01.y);
        a01.z = fmaf(qa.z, kb_.z, a01.z); a01.w = fmaf(qa.w, kb_.w, a01.w);
        a10.x = fmaf(qb_.x, ka.x, a10.x); a10.y = fmaf(qb_.y, ka.y, a10.y);
        a10.z = fmaf(qb_.z, ka.z, a10.z); a10.w = fmaf(qb_.w, ka.w, a10.w);
        a11.x = fmaf(qb_.x, kb_.x, a11.x); a11.y = fmaf(qb_.y, kb_.y, a11.y);
        a11.z = fmaf(qb_.z, kb_.z, a11.z); a11.w = fmaf(qb_.w, kb_.w, a11.w);
    }
    float* ar = attn_raw + ((size_t)b*4 + h) * 256;
    atomicAdd(&ar[(c0  )*16 + d0  ], hsum4(a00));
    atomicAdd(&ar[(c0  )*16 + d0+1], hsum4(a01));
    atomicAdd(&ar[(c0+1)*16 + d0  ], hsum4(a10));
    atomicAdd(&ar[(c0+1)*16 + d0+1], hsum4(a11));

    if (threadIdx.x < 16) {
        float s = 0.f;
        #pragma unroll
        for (int jj = 0; jj < 16; ++jj) s += sred[threadIdx.x + 16*jj];
        atomicAdd(&ssq[b*64 + h*16 + threadIdx.x], s);
    } else if (threadIdx.x < 32) {
        const int c2 = threadIdx.x - 16;
        float s = 0.f;
        #pragma unroll
        for (int jj = 0; jj < 16; ++jj) s += sred[256 + c2 + 16*jj];
        atomicAdd(&ssk[b*64 + h*16 + c2], s);
    }
}

// ---------------- softmax with l2-norm scaling + temperature ----------------
__global__ __launch_bounds__(256)
void attn_softmax_v2(const float* __restrict__ attn_raw,
                     const float* __restrict__ ssq, const float* __restrict__ ssk,
                     const float* __restrict__ temp, float* __restrict__ attn)
{
    const int h = blockIdx.x, b = blockIdx.y;
    const int c = threadIdx.x >> 4, d = threadIdx.x & 15;
    const float nq = fmaxf(sqrtf(ssq[b*64 + h*16 + c]), 1e-12f);
    const float nk = fmaxf(sqrtf(ssk[b*64 + h*16 + d]), 1e-12f);
    float logit = attn_raw[((size_t)b*4 + h)*256 + c*16 + d] / (nq * nk) * temp[h];
    float m = logit;
    #pragma unroll
    for (int o = 8; o; o >>= 1) m = fmaxf(m, __shfl_xor(m, o, 16));
    float e = expf(logit - m);
    float s = e;
    #pragma unroll
    for (int o = 8; o; o >>= 1) s += __shfl_xor(s, o, 16);
    attn[((size_t)b*4 + h)*256 + c*16 + d] = e / s;
}

// ---------------- M[b] = proj . blockdiag(attn[b]) ----------------
__global__ __launch_bounds__(256)
void build_m_v2(const float* __restrict__ attn, const float* __restrict__ proj_w,
                float* __restrict__ M)
{
    const int b = blockIdx.x;
    for (int i = threadIdx.x; i < 4096; i += 256) {
        int co = i >> 6, ci = i & 63;
        int h = ci >> 4, d = ci & 15;
        float s = 0.f;
        #pragma unroll
        for (int cc = 0; cc < 16; ++cc)
            s += proj_w[co*64 + h*16 + cc] * attn[((size_t)b*4 + h)*256 + cc*16 + d];
        M[(size_t)b*4096 + i] = s;
    }
}

extern "C" void kernel_launch(void* const* d_in, const int* in_sizes, int n_in,
                              void* d_out, int out_size, void* d_ws, size_t ws_size,
                              hipStream_t stream)
{
    const float* x       = (const float*)d_in[0];
    const float* y       = (const float*)d_in[1];
    const float* kv_w    = (const float*)d_in[2];
    const float* q_w     = (const float*)d_in[3];
    const float* proj_w  = (const float*)d_in[4];
    const float* kv_c0_w = (const float*)d_in[5];
    const float* kv_c0_b = (const float*)d_in[6];
    const float* kv_cs_w = (const float*)d_in[7];
    const float* kv_cs_b = (const float*)d_in[8];
    const float* kv_c1_w = (const float*)d_in[9];
    const float* kv_c1_b = (const float*)d_in[10];
    const float* kv_gn_g = (const float*)d_in[11];
    const float* kv_gn_b = (const float*)d_in[12];
    const float* q_c0_w  = (const float*)d_in[13];
    const float* q_c0_b  = (const float*)d_in[14];
    const float* q_cs_w  = (const float*)d_in[15];
    const float* q_cs_b  = (const float*)d_in[16];
    const float* q_c1_w  = (const float*)d_in[17];
    const float* q_c1_b  = (const float*)d_in[18];
    const float* q_gn_g  = (const float*)d_in[19];
    const float* q_gn_b  = (const float*)d_in[20];
    const float* temp    = (const float*)d_in[21];

    float* ws       = (float*)d_ws;
    float* statsKV  = ws;            // 4/batch  -> 16
    float* statsQ   = ws + 16;
    float* sumsq_k  = ws + 32;       // 64/batch -> 256
    float* sumsq_q  = ws + 288;
    float* attn_raw = ws + 544;      // 1024/batch -> 4096
    float* attn     = ws + 4640;
    float* Mw       = ws + 8736;     // 4096/batch -> 16384 (end 25120)
    char*  bigc     = (char*)d_ws + 131072;

    // same ws requirement as before: 3 x nb x 128ch bf16 regions = nb * 48 MiB
    const size_t perb_bytes = (size_t)192 * HW * 4;
    int nb = 1;
    if      (ws_size >= 131072 + 4*perb_bytes) nb = 4;
    else if (ws_size >= 131072 + 2*perb_bytes) nb = 2;

    hipMemsetAsync(d_ws, 0, 102400, stream);
    dim3 blk(256);

    for (int b0 = 0; b0 < 4; b0 += nb) {
        const float* xb = x + (size_t)b0*64*HW;
        const float* yb = y + (size_t)b0*64*HW;
        const size_t SZ = (size_t)nb * 128 * HW;          // ushorts per 128-ch region
        unsigned short* A  = (unsigned short*)bigc;        // kvpre-out (cs128); later Q1|Q2
        unsigned short* Bm = A + SZ;                       // dw-out KVmid (cs128); later QF
        unsigned short* C  = A + 2*SZ;                     // k | v_raw (cs128)
        unsigned short* Q1 = A;                            // cs64
        unsigned short* Q2 = A + (size_t)nb * 64 * HW;     // cs64
        unsigned short* QF = Bm;                           // cs64
        float* stK = statsKV + b0*4;
        float* stQ = statsQ  + b0*4;
        float* ssk = sumsq_k + b0*64;
        float* ssq = sumsq_q + b0*64;
        float* arw = attn_raw + b0*1024;
        float* atn = attn     + b0*1024;
        float* Mb  = Mw       + b0*4096;

        dim3 gdwf(4, 8, nb*64);
        dim3 gcv(128, nb);

        // ---- kv chain ----
        // y (NCHW fp32) -> A (blocked bf16, 128 ch)
        conv1x1_v10<64,128, 0,2, false><<<gcv, dim3(1024), 0, stream>>>(
            yb, 64, 0, kv_w, 0, nullptr, A, 128, 0,
            nullptr, 0, nullptr, nullptr, nullptr, 0, 0.f);
        // fused dw5x5+dw3x3d3 (bf16 in/out): A -> Bm (both halves into one cs128 tensor)
        dwfused16<<<gdwf, blk, 0, stream>>>(A, 128, 0,  kv_c0_w, kv_c0_b, 0,  kv_cs_w, kv_cs_b, 0,  Bm, 128, 0);
        dwfused16<<<gdwf, blk, 0, stream>>>(A, 128, 64, kv_c0_w, kv_c0_b, 64, kv_cs_w, kv_cs_b, 64, Bm, 128, 64);
        // 128->128 1x1: Bm bf16 -> C bf16 (k | v_raw), fp32 GN stats from accumulators
        conv1x1_v10<128,128, 2,2, false><<<gcv, dim3(1024), 0, stream>>>(
            Bm, 128, 0, kv_c1_w, 0, kv_c1_b, C, 128, 0,
            stK, -2, nullptr, nullptr, nullptr, 0, 0.f);

        // ---- q chain (reuses A after dwfused-kv consumed it, Bm after kvc1) ----
        conv1x1_v10<64,64, 0,2, false><<<gcv, dim3(512), 0, stream>>>(
            xb, 64, 0, q_w, 0, nullptr, Q1, 64, 0,
            nullptr, 0, nullptr, nullptr, nullptr, 0, 0.f);
        dwfused16<<<gdwf, blk, 0, stream>>>(Q1, 64, 0, q_c0_w, q_c0_b, 0, q_cs_w, q_cs_b, 0, Q2, 64, 0);
        conv1x1_v10<64,64, 2,2, false><<<gcv, dim3(512), 0, stream>>>(
            Q2, 64, 0, q_c1_w, 0, q_c1_b, QF, 64, 0,
            stQ, -1, nullptr, nullptr, nullptr, 0, 0.f);

        // ---- attention (bf16 q = QF cs64, k = C cs128) ----
        attn_dot_v6<<<dim3(128,4,nb), blk, 0, stream>>>(QF, 64, C, 128, stQ, stK,
                                                        q_gn_g, q_gn_b, kv_gn_g, kv_gn_b,
                                                        arw, ssq, ssk);
        attn_softmax_v2<<<dim3(4,nb), blk, 0, stream>>>(arw, ssq, ssk, temp, atn);
        build_m_v2<<<dim3(nb), blk, 0, stream>>>(atn, proj_w, Mb);

        // ---- out = M[b] @ leaky(GN(v_raw)); v_raw = C coff 64 bf16; out NCHW fp32 ----
        conv1x1_v10<64,64, 2,0, true><<<gcv, dim3(512), 0, stream>>>(
            C, 128, 64, Mw + b0*4096, 4096, nullptr,
            (float*)d_out + (size_t)b0*64*HW, 64, 0,
            nullptr, 0, stK+2, kv_gn_g, kv_gn_b, 64, 64.f*HW);
    }
}